// Round 2
// baseline (226.614 us; speedup 1.0000x reference)
//
#include <hip/hip_runtime.h>
#include <cstdint>
#include <cstddef>

#define TOKENS 4096
#define DM 512
#define DF 2048
#define NE 8
#define NPAIR 8192  // TOKENS * TOPK

typedef unsigned short u16;
typedef __attribute__((ext_vector_type(8))) short short8;
typedef __attribute__((ext_vector_type(4))) float f32x4;

// fp32 -> bf16 round-to-nearest-even (finite inputs only)
__device__ __forceinline__ u16 f2b(float x) {
  uint32_t u = __builtin_bit_cast(uint32_t, x);
  uint32_t r = (u + 0x7fffu + ((u >> 16) & 1u)) >> 16;
  return (u16)r;
}

__device__ __forceinline__ void gl_lds16(const void* gsrc, void* ldst) {
  __builtin_amdgcn_global_load_lds(
      (__attribute__((address_space(1))) void*)(gsrc),
      (__attribute__((address_space(3))) void*)(ldst), 16, 0, 0);
}

// ---------------- routing: build per-expert segments ----------------
__global__ void routing_kernel(const int* __restrict__ eidx,
                               int* __restrict__ pair_token,
                               int* __restrict__ pair_pos,
                               int* __restrict__ seg_off,
                               int* __restrict__ seg_cnt) {
  __shared__ int cnt[NE], off[NE], cur[NE];
  int tid = threadIdx.x;
  if (tid < NE) { cnt[tid] = 0; cur[tid] = 0; }
  __syncthreads();
  for (int i = tid; i < NPAIR; i += 256) atomicAdd(&cnt[eidx[i]], 1);
  __syncthreads();
  if (tid == 0) {
    int a = 0;
    for (int e = 0; e < NE; ++e) { off[e] = a; a += cnt[e]; }
  }
  __syncthreads();
  for (int i = tid; i < NPAIR; i += 256) {
    int e = eidx[i];
    int p = off[e] + atomicAdd(&cur[e], 1);
    pair_token[p] = i >> 1;  // token index
    pair_pos[i] = p;         // where this (token,k) landed
  }
  if (tid < NE) { seg_off[tid] = off[tid]; seg_cnt[tid] = cnt[tid]; }
}

// ---------------- hidden fp32 -> bf16 ----------------
__global__ void cvt_hidden_kernel(const float* __restrict__ in, u16* __restrict__ out) {
  int i = blockIdx.x * 256 + threadIdx.x;  // 4 elements each
  float4 v = ((const float4*)in)[i];
  ushort4 o;
  o.x = f2b(v.x); o.y = f2b(v.y); o.z = f2b(v.z); o.w = f2b(v.w);
  ((ushort4*)out)[i] = o;
}

// ---------------- transpose + convert: src[e][R][C] f32 -> dst[e][C][R] bf16 ----------------
// 64x64 tile, 256 threads. float4 global loads; ushort4 stores (128B segments).
// LDS padded to 65 -> transposed reads are 2-way conflicts only (free, m136).
template <int R, int C>
__global__ void tr_cvt_kernel(const float* __restrict__ src, u16* __restrict__ dst) {
  __shared__ float t[64][65];
  int e = blockIdx.z;
  int cb = blockIdx.x * 64, rb = blockIdx.y * 64;
  const float* s = src + (size_t)e * R * C;
  u16* d = dst + (size_t)e * R * C;
  int tid = threadIdx.x;
  int r = tid >> 4;    // 0..15
  int cq = tid & 15;   // col chunk of 4
#pragma unroll
  for (int i = 0; i < 4; ++i) {
    float4 v = *(const float4*)&s[(size_t)(rb + r + 16 * i) * C + cb + cq * 4];
    t[r + 16 * i][cq * 4 + 0] = v.x;
    t[r + 16 * i][cq * 4 + 1] = v.y;
    t[r + 16 * i][cq * 4 + 2] = v.z;
    t[r + 16 * i][cq * 4 + 3] = v.w;
  }
  __syncthreads();
  int rq = tid & 15;   // row chunk of 4 (inner dim of dst -> coalesced)
  int c0 = tid >> 4;   // 0..15
#pragma unroll
  for (int i = 0; i < 4; ++i) {
    int c = c0 + 16 * i;
    ushort4 o;
    o.x = f2b(t[rq * 4 + 0][c]);
    o.y = f2b(t[rq * 4 + 1][c]);
    o.z = f2b(t[rq * 4 + 2][c]);
    o.w = f2b(t[rq * 4 + 3][c]);
    *(ushort4*)&d[(size_t)(cb + c) * R + rb + rq * 4] = o;
  }
}

// ---------------- grouped GEMM, m97 structure, optional split-K ----------------
// C[m][n] = sum_{k in [sp*ks, sp*ks+ks)} A[row(m)][k] * Bt[n][k]
// tile 128x128, BK=32, 4 waves (2x2). blockIdx.x = (sp << sp_shift) | nt.
template <int KDIM, bool GATHER, bool RELU_BF16>
__global__ __launch_bounds__(256) void gemm_kernel(
    const u16* __restrict__ A,         // [*, KDIM] bf16 rows
    const u16* __restrict__ Bt,        // [NE][n_total][KDIM] bf16
    const int* __restrict__ pair_token,
    const int* __restrict__ seg_off, const int* __restrict__ seg_cnt,
    u16* __restrict__ out_b,           // act (RELU_BF16)
    float* __restrict__ out_f,         // Ypart (!RELU_BF16)
    int n_total, int nt_mask, int sp_shift, int ks) {
  const int e = blockIdx.z;
  const int cnt = seg_cnt[e];
  const int mt = blockIdx.y;
  if (mt * 128 >= cnt) return;
  const int off = seg_off[e];
  const int nt = blockIdx.x & nt_mask;
  const int sp = blockIdx.x >> sp_shift;
  const int kb = sp * ks, ke = kb + ks;
  const int tid = threadIdx.x;
  const int wave = tid >> 6, lane = tid & 63;

  __shared__ __align__(16) u16 Al[128 * 32];
  __shared__ __align__(16) u16 Bl[128 * 32];

  const int r0 = wave * 32;
  const int rr = lane >> 2;
  const int cc = (lane & 3) * 8;  // element offset (8 bf16 = 16B)

  const u16* aSrc[2];
  const u16* bSrc[2];
  const u16* BtBase = Bt + ((size_t)e * n_total + (size_t)nt * 128) * KDIM;
#pragma unroll
  for (int g = 0; g < 2; ++g) {
    int rl = r0 + g * 16 + rr;
    int m = mt * 128 + rl;
    if (m > cnt - 1) m = cnt - 1;  // clamp padding rows to valid data
    int srow = GATHER ? pair_token[off + m] : (off + m);
    aSrc[g] = A + (size_t)srow * KDIM + cc;
    bSrc[g] = BtBase + (size_t)rl * KDIM + cc;
  }

  const int wm = wave >> 1, wn = wave & 1;
  const int rl16 = lane & 15;
  const int kk = (lane >> 4) * 8;

  f32x4 acc[4][4];
#pragma unroll
  for (int i = 0; i < 4; ++i)
#pragma unroll
    for (int j = 0; j < 4; ++j)
#pragma unroll
      for (int r = 0; r < 4; ++r) acc[i][j][r] = 0.0f;

  for (int k0 = kb; k0 < ke; k0 += 32) {
#pragma unroll
    for (int g = 0; g < 2; ++g) {
      gl_lds16(aSrc[g] + k0, &Al[(r0 + g * 16) * 32]);
      gl_lds16(bSrc[g] + k0, &Bl[(r0 + g * 16) * 32]);
    }
    __syncthreads();
    short8 af[4], bf[4];
#pragma unroll
    for (int mi = 0; mi < 4; ++mi)
      af[mi] = *(const short8*)&Al[(wm * 64 + mi * 16 + rl16) * 32 + kk];
#pragma unroll
    for (int ni = 0; ni < 4; ++ni)
      bf[ni] = *(const short8*)&Bl[(wn * 64 + ni * 16 + rl16) * 32 + kk];
#pragma unroll
    for (int mi = 0; mi < 4; ++mi)
#pragma unroll
      for (int ni = 0; ni < 4; ++ni)
        acc[mi][ni] = __builtin_amdgcn_mfma_f32_16x16x32_bf16(af[mi], bf[ni], acc[mi][ni], 0, 0, 0);
    __syncthreads();
  }

  float* outp = RELU_BF16 ? nullptr : (out_f + (size_t)sp * NPAIR * DM);

  // epilogue: D[row][col]: col = lane&15, row = (lane>>4)*4 + reg
  const int rowq = (lane >> 4) * 4;
#pragma unroll
  for (int mi = 0; mi < 4; ++mi) {
#pragma unroll
    for (int r = 0; r < 4; ++r) {
      int m = mt * 128 + wm * 64 + mi * 16 + rowq + r;
      if (m < cnt) {
        size_t rowp = (size_t)(off + m) * n_total;
#pragma unroll
        for (int ni = 0; ni < 4; ++ni) {
          int n = nt * 128 + wn * 64 + ni * 16 + rl16;
          float v = acc[mi][ni][r];
          if (RELU_BF16) {
            v = v > 0.0f ? v : 0.0f;
            out_b[rowp + n] = f2b(v);
          } else {
            outp[rowp + n] = v;
          }
        }
      }
    }
  }
}

// ---------------- combine: next = c0*sum_s Yp[s][p0] + c1*sum_s Yp[s][p1]; where ----------------
__global__ void combine_kernel(const float* __restrict__ hidden,
                               const float* __restrict__ prob,
                               const int* __restrict__ pair_pos,
                               const float* __restrict__ Ypart,
                               float* __restrict__ out, int nsplit) {
  int i = blockIdx.x * 256 + threadIdx.x;  // group of 4 floats
  int t = i >> 7;                          // 128 groups per token (512/4)
  int g = i & 127;
  int p0 = pair_pos[2 * t], p1 = pair_pos[2 * t + 1];
  float c0 = 0.5f * prob[2 * t];
  float c1 = 0.25f * prob[2 * t + 1];
  float4 a = {0.f, 0.f, 0.f, 0.f}, b = {0.f, 0.f, 0.f, 0.f};
  for (int s = 0; s < nsplit; ++s) {
    const float4* Y = (const float4*)(Ypart + (size_t)s * NPAIR * DM);
    float4 va = Y[(size_t)p0 * 128 + g];
    float4 vb = Y[(size_t)p1 * 128 + g];
    a.x += va.x; a.y += va.y; a.z += va.z; a.w += va.w;
    b.x += vb.x; b.y += vb.y; b.z += vb.z; b.w += vb.w;
  }
  float4 h = ((const float4*)hidden)[i];
  float4 r, o;
  r.x = c0 * a.x + c1 * b.x;
  r.y = c0 * a.y + c1 * b.y;
  r.z = c0 * a.z + c1 * b.z;
  r.w = c0 * a.w + c1 * b.w;
  o.x = (r.x != 0.0f) ? r.x : h.x;
  o.y = (r.y != 0.0f) ? r.y : h.y;
  o.z = (r.z != 0.0f) ? r.z : h.z;
  o.w = (r.w != 0.0f) ? r.w : h.w;
  ((float4*)out)[i] = o;
}

extern "C" void kernel_launch(void* const* d_in, const int* in_sizes, int n_in,
                              void* d_out, int out_size, void* d_ws, size_t ws_size,
                              hipStream_t stream) {
  const float* hidden = (const float*)d_in[0];
  const float* prob = (const float*)d_in[1];
  const float* wi = (const float*)d_in[2];
  const float* wo = (const float*)d_in[3];
  const int* eidx = (const int*)d_in[4];
  float* out = (float*)d_out;

  char* ws = (char*)d_ws;
  u16* hidden_b = (u16*)(ws + 0);                     //  4 MB [4096][512] bf16
  u16* wi_t = (u16*)(ws + ((size_t)4 << 20));         // 16 MB [8][2048][512] bf16 (wi^T)
  u16* wo_t = (u16*)(ws + ((size_t)20 << 20));        // 16 MB [8][512][2048] bf16 (wo^T)
  u16* act = (u16*)(ws + ((size_t)36 << 20));         // 32 MB [8192][2048] bf16
  float* Ypart = (float*)(ws + ((size_t)68 << 20));   // split*16 MB [split][8192][512] f32

  // split-K factor for GEMM2, limited by available workspace
  size_t base = (size_t)68 << 20;
  size_t small = (size_t)(1 << 20);
  int split = 1;
  if (ws_size >= base + ((size_t)64 << 20) + small) split = 4;
  else if (ws_size >= base + ((size_t)32 << 20) + small) split = 2;

  char* smalls = ws + base + ((size_t)split << 24);  // split*16MB after Ypart
  int* pair_token = (int*)(smalls);
  int* pair_pos = (int*)(smalls + (64u << 10));
  int* seg_off = (int*)(smalls + (128u << 10));
  int* seg_cnt = (int*)(smalls + (128u << 10) + 256);

  hipLaunchKernelGGL(routing_kernel, dim3(1), dim3(256), 0, stream,
                     eidx, pair_token, pair_pos, seg_off, seg_cnt);
  hipLaunchKernelGGL(cvt_hidden_kernel, dim3(2048), dim3(256), 0, stream, hidden, hidden_b);
  hipLaunchKernelGGL((tr_cvt_kernel<512, 2048>), dim3(32, 8, 8), dim3(256), 0, stream, wi, wi_t);
  hipLaunchKernelGGL((tr_cvt_kernel<2048, 512>), dim3(8, 32, 8), dim3(256), 0, stream, wo, wo_t);
  // GEMM1: act = relu(hidden @ wi[e]) ; M=pairs, N=2048, K=512, no split
  hipLaunchKernelGGL((gemm_kernel<512, true, true>), dim3(16, 64, 8), dim3(256), 0, stream,
                     hidden_b, wi_t, pair_token, seg_off, seg_cnt, act, (float*)nullptr,
                     DF, 15, 4, 512);
  // GEMM2: Ypart[sp] = act @ wo[e] (K-chunk) ; M=pairs, N=512, K=2048/split
  hipLaunchKernelGGL((gemm_kernel<2048, false, false>), dim3(4 * split, 64, 8), dim3(256), 0, stream,
                     act, wo_t, (const int*)nullptr, seg_off, seg_cnt, (u16*)nullptr, Ypart,
                     DM, 3, 2, 2048 / split);
  hipLaunchKernelGGL(combine_kernel, dim3(2048), dim3(256), 0, stream,
                     hidden, prob, pair_pos, Ypart, out, split);
}

// Round 6
// 215.740 us; speedup vs baseline: 1.0504x; 1.0504x over previous
//
#include <hip/hip_runtime.h>
#include <cstdint>
#include <cstddef>

#define TOKENS 4096
#define DM 512
#define DF 2048
#define NE 8
#define NPAIR 8192  // TOKENS * TOPK
#define SPLIT 4     // split-K factor for GEMM2 (R2-proven with f32 partials)

typedef unsigned short u16;
typedef __attribute__((ext_vector_type(8))) short short8;
typedef __attribute__((ext_vector_type(4))) float f32x4;

// fp32 -> bf16 round-to-nearest-even (finite inputs only)
__device__ __forceinline__ u16 f2b(float x) {
  uint32_t u = __builtin_bit_cast(uint32_t, x);
  uint32_t r = (u + 0x7fffu + ((u >> 16) & 1u)) >> 16;
  return (u16)r;
}

__device__ __forceinline__ void gl_lds16(const void* gsrc, void* ldst) {
  __builtin_amdgcn_global_load_lds(
      (__attribute__((address_space(1))) void*)(gsrc),
      (__attribute__((address_space(3))) void*)(ldst), 16, 0, 0);
}

// ---------------- prep: one dispatch, four R2-verbatim bodies ----------------
// bid 0            : routing
// bid 1..2048      : hidden fp32 -> bf16
// bid 2049..4096   : tr wi  [8][512][2048] -> [8][2048][512]  (bx=f&31, by=(f>>5)&7, e=f>>8)
// bid 4097..6144   : tr wo  [8][2048][512] -> [8][512][2048]  (bx=f&7,  by=(f>>3)&31, e=f>>8)
__global__ __launch_bounds__(256) void prep_kernel(
    const int* __restrict__ eidx, const float* __restrict__ hidden, u16* __restrict__ hidden_b,
    const float* __restrict__ wi, u16* __restrict__ wi_t,
    const float* __restrict__ wo, u16* __restrict__ wo_t,
    int* __restrict__ pair_token, int* __restrict__ pair_pos,
    int* __restrict__ seg_off, int* __restrict__ seg_cnt) {
  __shared__ __align__(16) float t[64][65];  // 16640 B; block 0 reuses the first ints
  int bid = blockIdx.x;
  int tid = threadIdx.x;
  if (bid == 0) {
    // --- routing (R2 body) ---
    int* cnt = (int*)&t[0][0];
    int* off = cnt + 8;
    int* cur = cnt + 16;
    if (tid < NE) { cnt[tid] = 0; cur[tid] = 0; }
    __syncthreads();
    for (int i = tid; i < NPAIR; i += 256) atomicAdd(&cnt[eidx[i]], 1);
    __syncthreads();
    if (tid == 0) {
      int a = 0;
      for (int e = 0; e < NE; ++e) { off[e] = a; a += cnt[e]; }
    }
    __syncthreads();
    for (int i = tid; i < NPAIR; i += 256) {
      int e = eidx[i];
      int p = off[e] + atomicAdd(&cur[e], 1);
      pair_token[p] = i >> 1;  // token index
      pair_pos[i] = p;         // where this (token,k) landed
    }
    if (tid < NE) { seg_off[tid] = off[tid]; seg_cnt[tid] = cnt[tid]; }
  } else if (bid <= 2048) {
    // --- hidden cvt (R2 body) ---
    int i = (bid - 1) * 256 + tid;  // float4 group
    float4 v = ((const float4*)hidden)[i];
    ushort4 o;
    o.x = f2b(v.x); o.y = f2b(v.y); o.z = f2b(v.z); o.w = f2b(v.w);
    ((ushort4*)hidden_b)[i] = o;
  } else if (bid <= 4096) {
    // --- tr wi (R2 tr_cvt_kernel<512,2048> body) ---
    const int R = DM, C = DF;
    int f = bid - 2049;
    int e = f >> 8;
    int cb = (f & 31) * 64, rb = ((f >> 5) & 7) * 64;
    const float* s = wi + (size_t)e * R * C;
    u16* d = wi_t + (size_t)e * R * C;
    int r = tid >> 4, cq = tid & 15;
#pragma unroll
    for (int i = 0; i < 4; ++i) {
      float4 v = *(const float4*)&s[(size_t)(rb + r + 16 * i) * C + cb + cq * 4];
      t[r + 16 * i][cq * 4 + 0] = v.x;
      t[r + 16 * i][cq * 4 + 1] = v.y;
      t[r + 16 * i][cq * 4 + 2] = v.z;
      t[r + 16 * i][cq * 4 + 3] = v.w;
    }
    __syncthreads();
    int rq = tid & 15, c0 = tid >> 4;
#pragma unroll
    for (int i = 0; i < 4; ++i) {
      int c = c0 + 16 * i;
      ushort4 o;
      o.x = f2b(t[rq * 4 + 0][c]);
      o.y = f2b(t[rq * 4 + 1][c]);
      o.z = f2b(t[rq * 4 + 2][c]);
      o.w = f2b(t[rq * 4 + 3][c]);
      *(ushort4*)&d[(size_t)(cb + c) * R + rb + rq * 4] = o;
    }
  } else {
    // --- tr wo (R2 tr_cvt_kernel<2048,512> body) ---
    const int R = DF, C = DM;
    int f = bid - 4097;
    int e = f >> 8;
    int cb = (f & 7) * 64, rb = ((f >> 3) & 31) * 64;
    const float* s = wo + (size_t)e * R * C;
    u16* d = wo_t + (size_t)e * R * C;
    int r = tid >> 4, cq = tid & 15;
#pragma unroll
    for (int i = 0; i < 4; ++i) {
      float4 v = *(const float4*)&s[(size_t)(rb + r + 16 * i) * C + cb + cq * 4];
      t[r + 16 * i][cq * 4 + 0] = v.x;
      t[r + 16 * i][cq * 4 + 1] = v.y;
      t[r + 16 * i][cq * 4 + 2] = v.z;
      t[r + 16 * i][cq * 4 + 3] = v.w;
    }
    __syncthreads();
    int rq = tid & 15, c0 = tid >> 4;
#pragma unroll
    for (int i = 0; i < 4; ++i) {
      int c = c0 + 16 * i;
      ushort4 o;
      o.x = f2b(t[rq * 4 + 0][c]);
      o.y = f2b(t[rq * 4 + 1][c]);
      o.z = f2b(t[rq * 4 + 2][c]);
      o.w = f2b(t[rq * 4 + 3][c]);
      *(ushort4*)&d[(size_t)(cb + c) * R + rb + rq * 4] = o;
    }
  }
}

// ---------------- grouped GEMM, R2-verbatim (BK=32, z-grid, f32 split-K out) ----
// C[m][n] = sum_{k in [sp*ks, +ks)} A[row(m)][k] * Bt[n][k]; tile 128x128, 4 waves.
// blockIdx.x = (sp << sp_shift) | nt.
template <int KDIM, bool GATHER, bool RELU_BF16>
__global__ __launch_bounds__(256) void gemm_kernel(
    const u16* __restrict__ A,         // [*, KDIM] bf16 rows
    const u16* __restrict__ Bt,        // [NE][n_total][KDIM] bf16
    const int* __restrict__ pair_token,
    const int* __restrict__ seg_off, const int* __restrict__ seg_cnt,
    u16* __restrict__ out_b,           // act (RELU_BF16)
    float* __restrict__ out_f,         // Ypart (!RELU_BF16)
    int n_total, int nt_mask, int sp_shift, int ks) {
  const int e = blockIdx.z;
  const int cnt = seg_cnt[e];
  const int mt = blockIdx.y;
  if (mt * 128 >= cnt) return;
  const int off = seg_off[e];
  const int nt = blockIdx.x & nt_mask;
  const int sp = blockIdx.x >> sp_shift;
  const int kb = sp * ks, ke = kb + ks;
  const int tid = threadIdx.x;
  const int wave = tid >> 6, lane = tid & 63;

  __shared__ __align__(16) u16 Al[128 * 32];
  __shared__ __align__(16) u16 Bl[128 * 32];

  const int r0 = wave * 32;
  const int rr = lane >> 2;
  const int cc = (lane & 3) * 8;  // element offset (8 bf16 = 16B)

  const u16* aSrc[2];
  const u16* bSrc[2];
  const u16* BtBase = Bt + ((size_t)e * n_total + (size_t)nt * 128) * KDIM;
#pragma unroll
  for (int g = 0; g < 2; ++g) {
    int rl = r0 + g * 16 + rr;
    int m = mt * 128 + rl;
    if (m > cnt - 1) m = cnt - 1;  // clamp padding rows to valid data
    int srow = GATHER ? pair_token[off + m] : (off + m);
    aSrc[g] = A + (size_t)srow * KDIM + cc;
    bSrc[g] = BtBase + (size_t)rl * KDIM + cc;
  }

  const int wm = wave >> 1, wn = wave & 1;
  const int rl16 = lane & 15;
  const int kk = (lane >> 4) * 8;

  f32x4 acc[4][4];
#pragma unroll
  for (int i = 0; i < 4; ++i)
#pragma unroll
    for (int j = 0; j < 4; ++j)
#pragma unroll
      for (int r = 0; r < 4; ++r) acc[i][j][r] = 0.0f;

  for (int k0 = kb; k0 < ke; k0 += 32) {
#pragma unroll
    for (int g = 0; g < 2; ++g) {
      gl_lds16(aSrc[g] + k0, &Al[(r0 + g * 16) * 32]);
      gl_lds16(bSrc[g] + k0, &Bl[(r0 + g * 16) * 32]);
    }
    __syncthreads();
    short8 af[4], bf[4];
#pragma unroll
    for (int mi = 0; mi < 4; ++mi)
      af[mi] = *(const short8*)&Al[(wm * 64 + mi * 16 + rl16) * 32 + kk];
#pragma unroll
    for (int ni = 0; ni < 4; ++ni)
      bf[ni] = *(const short8*)&Bl[(wn * 64 + ni * 16 + rl16) * 32 + kk];
#pragma unroll
    for (int mi = 0; mi < 4; ++mi)
#pragma unroll
      for (int ni = 0; ni < 4; ++ni)
        acc[mi][ni] = __builtin_amdgcn_mfma_f32_16x16x32_bf16(af[mi], bf[ni], acc[mi][ni], 0, 0, 0);
    __syncthreads();
  }

  float* outp = RELU_BF16 ? nullptr : (out_f + (size_t)sp * NPAIR * DM);

  // epilogue: D[row][col]: col = lane&15, row = (lane>>4)*4 + reg
  const int rowq = (lane >> 4) * 4;
#pragma unroll
  for (int mi = 0; mi < 4; ++mi) {
#pragma unroll
    for (int r = 0; r < 4; ++r) {
      int m = mt * 128 + wm * 64 + mi * 16 + rowq + r;
      if (m < cnt) {
        size_t rowp = (size_t)(off + m) * n_total;
#pragma unroll
        for (int ni = 0; ni < 4; ++ni) {
          int n = nt * 128 + wn * 64 + ni * 16 + rl16;
          float v = acc[mi][ni][r];
          if (RELU_BF16) {
            v = v > 0.0f ? v : 0.0f;
            out_b[rowp + n] = f2b(v);
          } else {
            outp[rowp + n] = v;
          }
        }
      }
    }
  }
}

// ---------------- combine (R2-verbatim, f32 partials) ----------------
__global__ void combine_kernel(const float* __restrict__ hidden,
                               const float* __restrict__ prob,
                               const int* __restrict__ pair_pos,
                               const float* __restrict__ Ypart,
                               float* __restrict__ out, int nsplit) {
  int i = blockIdx.x * 256 + threadIdx.x;  // group of 4 floats
  int t = i >> 7;                          // 128 groups per token (512/4)
  int g = i & 127;
  int p0 = pair_pos[2 * t], p1 = pair_pos[2 * t + 1];
  float c0 = 0.5f * prob[2 * t];
  float c1 = 0.25f * prob[2 * t + 1];
  float4 a = {0.f, 0.f, 0.f, 0.f}, b = {0.f, 0.f, 0.f, 0.f};
  for (int s = 0; s < nsplit; ++s) {
    const float4* Y = (const float4*)(Ypart + (size_t)s * NPAIR * DM);
    float4 va = Y[(size_t)p0 * 128 + g];
    float4 vb = Y[(size_t)p1 * 128 + g];
    a.x += va.x; a.y += va.y; a.z += va.z; a.w += va.w;
    b.x += vb.x; b.y += vb.y; b.z += vb.z; b.w += vb.w;
  }
  float4 h = ((const float4*)hidden)[i];
  float4 r, o;
  r.x = c0 * a.x + c1 * b.x;
  r.y = c0 * a.y + c1 * b.y;
  r.z = c0 * a.z + c1 * b.z;
  r.w = c0 * a.w + c1 * b.w;
  o.x = (r.x != 0.0f) ? r.x : h.x;
  o.y = (r.y != 0.0f) ? r.y : h.y;
  o.z = (r.z != 0.0f) ? r.z : h.z;
  o.w = (r.w != 0.0f) ? r.w : h.w;
  ((float4*)out)[i] = o;
}

extern "C" void kernel_launch(void* const* d_in, const int* in_sizes, int n_in,
                              void* d_out, int out_size, void* d_ws, size_t ws_size,
                              hipStream_t stream) {
  const float* hidden = (const float*)d_in[0];
  const float* prob = (const float*)d_in[1];
  const float* wi = (const float*)d_in[2];
  const float* wo = (const float*)d_in[3];
  const int* eidx = (const int*)d_in[4];
  float* out = (float*)d_out;

  // R2-proven workspace layout (split=4, f32 partials)
  char* ws = (char*)d_ws;
  u16* hidden_b = (u16*)(ws + 0);                     //  4 MB [4096][512] bf16
  u16* wi_t = (u16*)(ws + ((size_t)4 << 20));         // 16 MB [8][2048][512] bf16 (wi^T)
  u16* wo_t = (u16*)(ws + ((size_t)20 << 20));        // 16 MB [8][512][2048] bf16 (wo^T)
  u16* act = (u16*)(ws + ((size_t)36 << 20));         // 32 MB [8192][2048] bf16
  float* Ypart = (float*)(ws + ((size_t)68 << 20));   // 64 MB [4][8192][512] f32
  char* smalls = ws + ((size_t)132 << 20);
  int* pair_token = (int*)(smalls);
  int* pair_pos = (int*)(smalls + (64u << 10));
  int* seg_off = (int*)(smalls + (128u << 10));
  int* seg_cnt = (int*)(smalls + (128u << 10) + 256);

  // 1) prep: routing | hidden cvt | tr wi | tr wo — fused into one dispatch
  hipLaunchKernelGGL(prep_kernel, dim3(6145), dim3(256), 0, stream,
                     eidx, hidden, hidden_b, wi, wi_t, wo, wo_t,
                     pair_token, pair_pos, seg_off, seg_cnt);
  // 2) GEMM1: act = relu(hidden @ wi[e]); K=512, N=2048 (R2-verbatim launch)
  hipLaunchKernelGGL((gemm_kernel<DM, true, true>), dim3(16, 64, NE), dim3(256), 0, stream,
                     hidden_b, wi_t, pair_token, seg_off, seg_cnt, act, (float*)nullptr,
                     DF, 15, 4, DM);
  // 3) GEMM2: Ypart[sp] = act @ wo[e] (f32 partials); K=2048, split 4 (R2-verbatim)
  hipLaunchKernelGGL((gemm_kernel<DF, false, false>), dim3(4 * SPLIT, 64, NE), dim3(256), 0, stream,
                     act, wo_t, (const int*)nullptr, seg_off, seg_cnt, (u16*)nullptr, Ypart,
                     DM, 3, 2, DF / SPLIT);
  // 4) combine + where(next!=0, next, hidden) (R2-verbatim)
  hipLaunchKernelGGL(combine_kernel, dim3(2048), dim3(256), 0, stream,
                     hidden, prob, pair_pos, Ypart, out, SPLIT);
}